// Round 3
// baseline (232.770 us; speedup 1.0000x reference)
//
#include <hip/hip_runtime.h>

typedef __bf16 bf16x8 __attribute__((ext_vector_type(8)));
typedef __bf16 bf16x4 __attribute__((ext_vector_type(4)));
typedef float  f32x4  __attribute__((ext_vector_type(4)));

#define BM 128
#define BN 128
#define BK 64

__device__ __forceinline__ void g2l16(const void* g, void* l) {
    __builtin_amdgcn_global_load_lds((const __attribute__((address_space(1))) void*)g,
                                     (__attribute__((address_space(3))) void*)l, 16, 0, 0);
}

// NT GEMM: C[i][j] = sum_k A[i*lda+k] * B[j*ldb+k]  (+ epilogue)
// 128x128 tile, BK=64, 4 waves in 2x2, each wave 64x64.
// Main-loop LDS: unpadded [128][64] bf16, 16B-unit XOR swizzle (unit ^= row&7)
// applied at the global SOURCE column (global_load_lds dest is wave-uniform
// base + lane*16) and at fragment reads -> 0 bank conflicts (verified R2).
// Epilogue: acc -> padded LDS tile (write aliasing <=2-way = free), read back
// row-contiguous, 16B vector global stores = full 128B line writes.
// EPI: 2 = exp, bf16 row-major store                        [logits -> E]
//      3 = fp32 row-major store                             [PV -> out]
//      4 = +bias projection; z<2 bf16 row-major (q,k), z==2 transposed vT
template<int EPI>
__global__ __launch_bounds__(256)
void gemm_nt(const __bf16* __restrict__ A, const __bf16* __restrict__ B,
             void* __restrict__ Cv, const float* __restrict__ bias,
             int lda, int ldb, int ldc, int K,
             long sA, long sB, long sC)
{
    __shared__ __align__(16) char smem[36864];
    __bf16* As = (__bf16*)smem;            // [128*64]
    __bf16* Bs = (__bf16*)(smem + 16384);  // [128*64]

    const int tid  = threadIdx.x;
    const int w    = tid >> 6;
    const int lane = tid & 63;
    const int quad = lane >> 4;
    const int l16  = lane & 15;
    const int wm   = w & 1;
    const int wn   = w >> 1;

    const int m0 = blockIdx.x * BM;
    const int n0 = blockIdx.y * BN;
    const int z  = blockIdx.z;

    const __bf16* Ab = A + (size_t)z * sA;
    const __bf16* Bb = B + (size_t)z * sB;

    const int srow = (w << 3) + (lane >> 3);
    const int scol = ((lane & 7) ^ (lane >> 3)) << 3;
    char* ldsA = (char*)As + (size_t)w * 1024;
    char* ldsB = (char*)Bs + (size_t)w * 1024;

    const __bf16* Ag = Ab + (size_t)(m0 + srow) * lda + scol;
    const __bf16* Bg = Bb + (size_t)(n0 + srow) * ldb + scol;

    f32x4 acc[4][4] = {};

    for (int k0 = 0; k0 < K; k0 += BK) {
        __syncthreads();
        #pragma unroll
        for (int c = 0; c < 4; c++)
            g2l16(Ag + (size_t)(c * 32) * lda + k0, ldsA + c * 4096);
        #pragma unroll
        for (int c = 0; c < 4; c++)
            g2l16(Bg + (size_t)(c * 32) * ldb + k0, ldsB + c * 4096);
        __syncthreads();

        #pragma unroll
        for (int kk = 0; kk < BK; kk += 32) {
            const int ub = kk >> 3;
            bf16x8 a[4], b[4];
            #pragma unroll
            for (int mt = 0; mt < 4; mt++) {
                const int row = wm * 64 + mt * 16 + l16;
                const int cp  = ((quad + ub) ^ (row & 7)) << 3;
                a[mt] = *(const bf16x8*)&As[row * BK + cp];
            }
            #pragma unroll
            for (int nt = 0; nt < 4; nt++) {
                const int row = wn * 64 + nt * 16 + l16;
                const int cp  = ((quad + ub) ^ (row & 7)) << 3;
                b[nt] = *(const bf16x8*)&Bs[row * BK + cp];
            }
            #pragma unroll
            for (int mt = 0; mt < 4; mt++)
                #pragma unroll
                for (int nt = 0; nt < 4; nt++)
                    acc[mt][nt] = __builtin_amdgcn_mfma_f32_16x16x32_bf16(
                        a[mt], b[nt], acc[mt][nt], 0, 0, 0);
        }
    }

    // ---- Epilogue (C/D layout m89/m91: row = quad*4 + reg, col = l16) ----
    __syncthreads();   // As/Bs dead; smem reused below

    if constexpr (EPI == 2 || EPI == 4) {
        __bf16* eb = (__bf16*)smem;   // [128][144] bf16, 36864 B
        const bool tr = (EPI == 4) && (z == 2);
        if (!tr) {
            float bn[4];
            if constexpr (EPI == 4) {
                #pragma unroll
                for (int nt = 0; nt < 4; nt++)
                    bn[nt] = bias[z * 256 + n0 + wn * 64 + nt * 16 + l16];
            }
            #pragma unroll
            for (int mt = 0; mt < 4; mt++) {
                const int row = wm * 64 + mt * 16 + quad * 4;
                #pragma unroll
                for (int nt = 0; nt < 4; nt++) {
                    const int col = wn * 64 + nt * 16 + l16;
                    #pragma unroll
                    for (int r = 0; r < 4; r++) {
                        float v = acc[mt][nt][r];
                        if constexpr (EPI == 2) v = __expf(v);
                        else                    v += bn[nt];
                        eb[(row + r) * 144 + col] = (__bf16)v;
                    }
                }
            }
        } else {
            // transposed: eb[d_local][m_local]; 4 regs = 4 consecutive m -> b64 pack
            #pragma unroll
            for (int nt = 0; nt < 4; nt++) {
                const float bn = bias[z * 256 + n0 + wn * 64 + nt * 16 + l16];
                const int erow = wn * 64 + nt * 16 + l16;
                #pragma unroll
                for (int mt = 0; mt < 4; mt++) {
                    bf16x4 pk;
                    #pragma unroll
                    for (int r = 0; r < 4; r++) pk[r] = (__bf16)(acc[mt][nt][r] + bn);
                    *(bf16x4*)&eb[erow * 144 + wm * 64 + mt * 16 + quad * 4] = pk;
                }
            }
        }
        __syncthreads();
        const int row = tid >> 1, seg = tid & 1;
        __bf16* dst;
        if (!tr) {
            dst = (__bf16*)Cv + (size_t)z * sC + (size_t)(m0 + row) * ldc + n0 + seg * 64;
        } else {
            // vT[b][d][m]: batch stride 262144, d stride 1024
            dst = (__bf16*)Cv + 2 * sC + (size_t)(m0 >> 10) * 262144
                + (size_t)(n0 + row) * 1024 + (m0 & 1023) + seg * 64;
        }
        #pragma unroll
        for (int u = 0; u < 8; u++)
            *(bf16x8*)(dst + u * 8) = *(const bf16x8*)&eb[row * 144 + seg * 64 + u * 8];
    } else {
        // EPI 3: fp32 out, two row-half passes through [64][132] fp32 (33792 B)
        float* ef = (float*)smem;
        float* C  = (float*)Cv + (size_t)z * sC;
        #pragma unroll
        for (int h = 0; h < 2; h++) {
            if (h) __syncthreads();
            if (wm == h) {
                #pragma unroll
                for (int mt = 0; mt < 4; mt++) {
                    const int row = mt * 16 + quad * 4;
                    #pragma unroll
                    for (int nt = 0; nt < 4; nt++) {
                        const int col = wn * 64 + nt * 16 + l16;
                        #pragma unroll
                        for (int r = 0; r < 4; r++)
                            ef[(row + r) * 132 + col] = acc[mt][nt][r];
                    }
                }
            }
            __syncthreads();
            const int row = tid >> 2, seg = tid & 3;
            float* dst = C + (size_t)(m0 + h * 64 + row) * ldc + n0 + seg * 32;
            #pragma unroll
            for (int u = 0; u < 8; u++)
                *(f32x4*)(dst + u * 4) = *(const f32x4*)&ef[row * 132 + seg * 32 + u * 4];
        }
    }
}

// One launch: x -> bf16, Wq/Wk/Wv -> bf16, and pack the 3 fp32 biases.
__global__ __launch_bounds__(256)
void cvt_all(const float* __restrict__ x,
             const float* __restrict__ Wq, const float* __restrict__ Wk,
             const float* __restrict__ Wv,
             const float* __restrict__ bq, const float* __restrict__ bk,
             const float* __restrict__ bv,
             __bf16* __restrict__ xb, __bf16* __restrict__ Wqb,
             float* __restrict__ bpack)
{
    const int i = blockIdx.x * 256 + threadIdx.x;
    if (i < 1073152) {
        const float* s; __bf16* d; int off;
        if (i < 1048576)      { s = x;  d = xb;            off = i; }
        else if (i < 1056768) { s = Wq; d = Wqb;           off = i - 1048576; }
        else if (i < 1064960) { s = Wk; d = Wqb + 131072;  off = i - 1056768; }
        else                  { s = Wv; d = Wqb + 262144;  off = i - 1064960; }
        const float4* s4 = (const float4*)s;
        const float4 f0 = s4[off * 2], f1 = s4[off * 2 + 1];
        bf16x8 o;
        o[0] = (__bf16)f0.x; o[1] = (__bf16)f0.y; o[2] = (__bf16)f0.z; o[3] = (__bf16)f0.w;
        o[4] = (__bf16)f1.x; o[5] = (__bf16)f1.y; o[6] = (__bf16)f1.z; o[7] = (__bf16)f1.w;
        ((bf16x8*)d)[off] = o;
    } else if (i < 1073344) {
        const int j = i - 1073152;          // 0..191, float4 units
        const int sel = j >> 6, jj = j & 63;
        const float* s = sel == 0 ? bq : (sel == 1 ? bk : bv);
        ((float4*)bpack)[j] = ((const float4*)s)[jj];
    }
}

// Batch-axis softmax: S[n,m] = sum_b E[b,n,m]; E <- E/S. Single pass:
// all 32 batch slices cached in registers (32 x bf16x8 = 128 VGPR).
__global__ __launch_bounds__(256)
void softmax_norm(__bf16* __restrict__ E)
{
    const size_t p = (size_t)blockIdx.x * 256 + threadIdx.x;
    bf16x8* E8 = (bf16x8*)E;
    bf16x8 e[32];
    #pragma unroll
    for (int b = 0; b < 32; b++) e[b] = E8[(size_t)b * 131072 + p];
    float s[8] = {0.f, 0.f, 0.f, 0.f, 0.f, 0.f, 0.f, 0.f};
    #pragma unroll
    for (int b = 0; b < 32; b++)
        #pragma unroll
        for (int j = 0; j < 8; j++) s[j] += (float)e[b][j];
    float rs[8];
    #pragma unroll
    for (int j = 0; j < 8; j++) rs[j] = 1.0f / s[j];
    #pragma unroll
    for (int b = 0; b < 32; b++) {
        bf16x8 o = e[b];
        #pragma unroll
        for (int j = 0; j < 8; j++) o[j] = (__bf16)((float)o[j] * rs[j]);
        E8[(size_t)b * 131072 + p] = o;
    }
}

extern "C" void kernel_launch(void* const* d_in, const int* in_sizes, int n_in,
                              void* d_out, int out_size, void* d_ws, size_t ws_size,
                              hipStream_t stream)
{
    const float* x  = (const float*)d_in[0];
    const float* Wq = (const float*)d_in[1];
    const float* bq = (const float*)d_in[2];
    const float* Wk = (const float*)d_in[3];
    const float* bk = (const float*)d_in[4];
    const float* Wv = (const float*)d_in[5];
    const float* bv = (const float*)d_in[6];
    float* out = (float*)d_out;

    // Workspace layout (bytes):
    //   [0,16M)    xb   bf16 (32768 x 256)
    //   [16M,32M)  qb   bf16           \
    //   [32M,48M)  kb   bf16            } contiguous, stride 16M (8388608 elem)
    //   [48M,64M)  vT   bf16 (32,256,1024)
    //   [64M,128M) E    bf16 (32,1024,1024)
    //   [128M,+768K) Wqb/Wkb/Wvb bf16 (contiguous, 131072 elem each)
    //   [+768K,+771K) bpack fp32[768]
    char* ws = (char*)d_ws;
    __bf16* xb    = (__bf16*)(ws);
    __bf16* qkv   = (__bf16*)(ws + (16u << 20));   // qb base; kb,vT follow at 16M strides
    __bf16* E     = (__bf16*)(ws + (64u << 20));
    __bf16* Wqb   = (__bf16*)(ws + (128u << 20));
    float*  bpack = (float*) (ws + (128u << 20) + (3u << 18));

    // 1) converts + bias pack (one launch)
    cvt_all<<<4194, 256, 0, stream>>>(x, Wq, Wk, Wv, bq, bk, bv, xb, Wqb, bpack);

    // 2) q/k/v projections in one launch: z in {0,1,2} picks W/bias/output.
    //    M=32768, N=256, K=256; sB = weight stride, sC = output stride.
    gemm_nt<4><<<dim3(256, 2, 3), 256, 0, stream>>>(xb, Wqb, qkv, bpack,
                                                    256, 256, 256, 256,
                                                    0, 131072, 8388608);

    // 3) E[b] = exp(q[b] @ k[b]^T): per-batch M=N=1024, K=256
    gemm_nt<2><<<dim3(8, 8, 32), 256, 0, stream>>>(qkv, qkv + 8388608, E, nullptr,
                                                   256, 256, 1024, 256,
                                                   262144, 262144, 1048576);

    // 4) batch-axis softmax normalize (in place, single pass)
    softmax_norm<<<512, 256, 0, stream>>>(E);

    // 5) out[b] = attn[b] @ vT[b]^T: per-batch M=1024, N=256, K=1024, fp32 out
    gemm_nt<3><<<dim3(8, 2, 32), 256, 0, stream>>>(E, qkv + 2 * 8388608, out, nullptr,
                                                   1024, 1024, 256, 1024,
                                                   1048576, 262144, 262144);
}

// Round 4
// 213.464 us; speedup vs baseline: 1.0904x; 1.0904x over previous
//
#include <hip/hip_runtime.h>

typedef __bf16 bf16x8 __attribute__((ext_vector_type(8)));
typedef __bf16 bf16x4 __attribute__((ext_vector_type(4)));
typedef float  f32x4  __attribute__((ext_vector_type(4)));

#define BM 128
#define BN 128
#define BK 64

__device__ __forceinline__ void g2l16(const void* g, void* l) {
    __builtin_amdgcn_global_load_lds((const __attribute__((address_space(1))) void*)g,
                                     (__attribute__((address_space(3))) void*)l, 16, 0, 0);
}

// NT GEMM: C[i][j] = sum_k A[i*lda+k] * B[j*ldb+k]  (+ epilogue)
// 128x128 tile, BK=64, 4 waves 2x2, wave computes 64x64.
// LDS: unpadded [128][64] bf16, 16B-unit XOR swizzle (unit ^= row&7) applied
// at the global SOURCE column during global_load_lds staging and at fragment
// reads -> 0 bank conflicts (verified R2).
// Epilogue: DIRECT global stores (R2-verified: L2 merges the per-wave 128B
// row coverage, WRITE_SIZE shows no amplification; R3's LDS roundtrip had
// bank conflicts and regressed).
// EPI: 2 = exp -> bf16 row-major store                      [logits -> E]
//      4 = +bias projection; z<2 bf16 row-major (q,k), z==2 transposed vT
// FLAT: decode flat blockIdx.x as id = xy*32 + z  (=> id%8 == z%8, so all
// blocks of one batch land on one XCD under round-robin assignment).
template<int EPI, int FLAT>
__global__ __launch_bounds__(256)
void gemm_nt(const __bf16* __restrict__ A, const __bf16* __restrict__ B,
             void* __restrict__ Cv, const float* __restrict__ bias,
             int lda, int ldb, int ldc, int K,
             long sA, long sB, long sC)
{
    __shared__ __align__(16) __bf16 As[BM * BK];
    __shared__ __align__(16) __bf16 Bs[BN * BK];

    const int tid  = threadIdx.x;
    const int w    = tid >> 6;
    const int lane = tid & 63;
    const int quad = lane >> 4;
    const int l16  = lane & 15;
    const int wm   = w & 1;
    const int wn   = w >> 1;

    int m0, n0, z;
    if constexpr (FLAT) {
        const int id = blockIdx.x;
        z = id & 31;
        const int xy = id >> 5;
        m0 = (xy & 7) * BM;
        n0 = (xy >> 3) * BN;
    } else {
        m0 = blockIdx.x * BM;
        n0 = blockIdx.y * BN;
        z  = blockIdx.z;
    }

    const __bf16* Ab = A + (size_t)z * sA;
    const __bf16* Bb = B + (size_t)z * sB;

    const int srow = (w << 3) + (lane >> 3);
    const int scol = ((lane & 7) ^ (lane >> 3)) << 3;
    char* ldsA = (char*)As + (size_t)w * 1024;
    char* ldsB = (char*)Bs + (size_t)w * 1024;

    const __bf16* Ag = Ab + (size_t)(m0 + srow) * lda + scol;
    const __bf16* Bg = Bb + (size_t)(n0 + srow) * ldb + scol;

    f32x4 acc[4][4] = {};

    for (int k0 = 0; k0 < K; k0 += BK) {
        __syncthreads();
        #pragma unroll
        for (int c = 0; c < 4; c++)
            g2l16(Ag + (size_t)(c * 32) * lda + k0, ldsA + c * 4096);
        #pragma unroll
        for (int c = 0; c < 4; c++)
            g2l16(Bg + (size_t)(c * 32) * ldb + k0, ldsB + c * 4096);
        __syncthreads();

        #pragma unroll
        for (int kk = 0; kk < BK; kk += 32) {
            const int ub = kk >> 3;
            bf16x8 a[4], b[4];
            #pragma unroll
            for (int mt = 0; mt < 4; mt++) {
                const int row = wm * 64 + mt * 16 + l16;
                const int cp  = ((quad + ub) ^ (row & 7)) << 3;
                a[mt] = *(const bf16x8*)&As[row * BK + cp];
            }
            #pragma unroll
            for (int nt = 0; nt < 4; nt++) {
                const int row = wn * 64 + nt * 16 + l16;
                const int cp  = ((quad + ub) ^ (row & 7)) << 3;
                b[nt] = *(const bf16x8*)&Bs[row * BK + cp];
            }
            #pragma unroll
            for (int mt = 0; mt < 4; mt++)
                #pragma unroll
                for (int nt = 0; nt < 4; nt++)
                    acc[mt][nt] = __builtin_amdgcn_mfma_f32_16x16x32_bf16(
                        a[mt], b[nt], acc[mt][nt], 0, 0, 0);
        }
    }

    // Epilogue. C/D layout (m89/m91): row = quad*4 + reg, col = l16.
    #pragma unroll
    for (int mt = 0; mt < 4; mt++) {
        const int mb = m0 + wm * 64 + mt * 16 + quad * 4;
        #pragma unroll
        for (int nt = 0; nt < 4; nt++) {
            const int n = n0 + wn * 64 + nt * 16 + l16;
            if constexpr (EPI == 2) {
                __bf16* C = (__bf16*)Cv + (size_t)z * sC;
                #pragma unroll
                for (int r = 0; r < 4; r++)
                    C[(size_t)(mb + r) * ldc + n] = (__bf16)__expf(acc[mt][nt][r]);
            } else {  // EPI == 4
                const float bn = bias[z * 256 + n];
                if (z < 2) {
                    __bf16* C = (__bf16*)Cv + (size_t)z * sC;
                    #pragma unroll
                    for (int r = 0; r < 4; r++)
                        C[(size_t)(mb + r) * ldc + n] = (__bf16)(acc[mt][nt][r] + bn);
                } else {
                    // vT[b][d=n][m]: batch stride 262144, d stride 1024
                    __bf16* C = (__bf16*)Cv + 2 * sC;
                    const int bidx = mb >> 10, mloc = mb & 1023;  // mb multiple of 4
                    bf16x4 pk;
                    #pragma unroll
                    for (int r = 0; r < 4; r++) pk[r] = (__bf16)(acc[mt][nt][r] + bn);
                    *(bf16x4*)(C + (size_t)bidx * 262144 + (size_t)n * 1024 + mloc) = pk;
                }
            }
        }
    }
}

// PV GEMM with fused batch-softmax normalization:
// out[z] = (E[z] * Srcp) @ vT[z]^T, Srcp[n,m] = 1/sum_b E[b,n,m] (fp32).
// A (E) is staged via VGPR roundtrip (load bf16x8, scale by Srcp, swizzled
// ds_write_b128 -> even 8-dword/bank spread = inherent floor, no extra
// conflicts). B (vT) stays on the global_load_lds path.
__global__ __launch_bounds__(256)
void gemm_pv(const __bf16* __restrict__ E, const float* __restrict__ Srcp,
             const __bf16* __restrict__ vT, float* __restrict__ out)
{
    __shared__ __align__(16) __bf16 As[128 * 64];
    __shared__ __align__(16) __bf16 Bs[128 * 64];

    const int tid  = threadIdx.x;
    const int w    = tid >> 6;
    const int lane = tid & 63;
    const int quad = lane >> 4;
    const int l16  = lane & 15;
    const int wm   = w & 1;
    const int wn   = w >> 1;

    const int id = blockIdx.x;            // flat 512: z->XCD swizzle
    const int z  = id & 31;
    const int xy = id >> 5;                // 0..15
    const int m0 = (xy & 7) * 128;         // output-row (n) tile
    const int n0 = (xy >> 3) * 128;        // output-col (d) tile

    const __bf16* Eb = E  + (size_t)z * 1048576;
    const __bf16* Vb = vT + (size_t)z * 262144;
    float*        Ob = out + (size_t)z * 262144;

    // B staging (global_load_lds, swizzled source col)
    const int srow = (w << 3) + (lane >> 3);
    const int scol = ((lane & 7) ^ (lane >> 3)) << 3;
    char* ldsB = (char*)Bs + (size_t)w * 1024;
    const __bf16* Bg = Vb + (size_t)(n0 + srow) * 1024 + scol;

    // A staging (VGPR roundtrip + normalize): thread owns row = tid>>1,
    // 8-col units (tid&1)*4 + s, s=0..3.
    const int arow = tid >> 1;
    const int auh  = (tid & 1) * 4;
    const __bf16* Ag = Eb + (size_t)(m0 + arow) * 1024;
    const float*  Sg = Srcp + (size_t)(m0 + arow) * 1024;
    __bf16* Ad = As + arow * 64;

    f32x4 acc[4][4] = {};

    for (int k0 = 0; k0 < 1024; k0 += BK) {
        __syncthreads();
        #pragma unroll
        for (int c = 0; c < 4; c++)
            g2l16(Bg + (size_t)(c * 32) * 1024 + k0, ldsB + c * 4096);
        #pragma unroll
        for (int s = 0; s < 4; s++) {
            const int u   = auh + s;
            const int col = k0 + u * 8;
            bf16x8 e  = *(const bf16x8*)(Ag + col);
            f32x4  r0 = *(const f32x4*)(Sg + col);
            f32x4  r1 = *(const f32x4*)(Sg + col + 4);
            bf16x8 en;
            en[0] = (__bf16)((float)e[0] * r0[0]);
            en[1] = (__bf16)((float)e[1] * r0[1]);
            en[2] = (__bf16)((float)e[2] * r0[2]);
            en[3] = (__bf16)((float)e[3] * r0[3]);
            en[4] = (__bf16)((float)e[4] * r1[0]);
            en[5] = (__bf16)((float)e[5] * r1[1]);
            en[6] = (__bf16)((float)e[6] * r1[2]);
            en[7] = (__bf16)((float)e[7] * r1[3]);
            *(bf16x8*)(Ad + ((u ^ (arow & 7)) << 3)) = en;
        }
        __syncthreads();

        #pragma unroll
        for (int kk = 0; kk < BK; kk += 32) {
            const int ub = kk >> 3;
            bf16x8 a[4], b[4];
            #pragma unroll
            for (int mt = 0; mt < 4; mt++) {
                const int row = wm * 64 + mt * 16 + l16;
                const int cp  = ((quad + ub) ^ (row & 7)) << 3;
                a[mt] = *(const bf16x8*)&As[row * BK + cp];
            }
            #pragma unroll
            for (int nt = 0; nt < 4; nt++) {
                const int row = wn * 64 + nt * 16 + l16;
                const int cp  = ((quad + ub) ^ (row & 7)) << 3;
                b[nt] = *(const bf16x8*)&Bs[row * BK + cp];
            }
            #pragma unroll
            for (int mt = 0; mt < 4; mt++)
                #pragma unroll
                for (int nt = 0; nt < 4; nt++)
                    acc[mt][nt] = __builtin_amdgcn_mfma_f32_16x16x32_bf16(
                        a[mt], b[nt], acc[mt][nt], 0, 0, 0);
        }
    }

    #pragma unroll
    for (int mt = 0; mt < 4; mt++) {
        const int mb = m0 + wm * 64 + mt * 16 + quad * 4;
        #pragma unroll
        for (int nt = 0; nt < 4; nt++) {
            const int n = n0 + wn * 64 + nt * 16 + l16;
            #pragma unroll
            for (int r = 0; r < 4; r++)
                Ob[(size_t)(mb + r) * 256 + n] = acc[mt][nt][r];
        }
    }
}

// One launch: x -> bf16, Wq/Wk/Wv -> bf16, pack 3 fp32 biases.
__global__ __launch_bounds__(256)
void cvt_all(const float* __restrict__ x,
             const float* __restrict__ Wq, const float* __restrict__ Wk,
             const float* __restrict__ Wv,
             const float* __restrict__ bq, const float* __restrict__ bk,
             const float* __restrict__ bv,
             __bf16* __restrict__ xb, __bf16* __restrict__ Wqb,
             float* __restrict__ bpack)
{
    const int i = blockIdx.x * 256 + threadIdx.x;
    if (i < 1073152) {
        const float* s; __bf16* d; int off;
        if (i < 1048576)      { s = x;  d = xb;            off = i; }
        else if (i < 1056768) { s = Wq; d = Wqb;           off = i - 1048576; }
        else if (i < 1064960) { s = Wk; d = Wqb + 131072;  off = i - 1056768; }
        else                  { s = Wv; d = Wqb + 262144;  off = i - 1064960; }
        const float4* s4 = (const float4*)s;
        const float4 f0 = s4[off * 2], f1 = s4[off * 2 + 1];
        bf16x8 o;
        o[0] = (__bf16)f0.x; o[1] = (__bf16)f0.y; o[2] = (__bf16)f0.z; o[3] = (__bf16)f0.w;
        o[4] = (__bf16)f1.x; o[5] = (__bf16)f1.y; o[6] = (__bf16)f1.z; o[7] = (__bf16)f1.w;
        ((bf16x8*)d)[off] = o;
    } else if (i < 1073344) {
        const int j = i - 1073152;
        const int sel = j >> 6, jj = j & 63;
        const float* s = sel == 0 ? bq : (sel == 1 ? bk : bv);
        ((float4*)bpack)[j] = ((const float4*)s)[jj];
    }
}

// Srcp[n,m] = 1 / sum_b E[b,n,m]  (fp32, 4 MB)
__global__ __launch_bounds__(256)
void reduce_s(const __bf16* __restrict__ E, float* __restrict__ Srcp)
{
    const size_t p = (size_t)blockIdx.x * 256 + threadIdx.x;  // bf16x8 unit
    const bf16x8* E8 = (const bf16x8*)E;
    float s[8] = {0.f, 0.f, 0.f, 0.f, 0.f, 0.f, 0.f, 0.f};
    #pragma unroll
    for (int b = 0; b < 32; b++) {
        bf16x8 e = E8[(size_t)b * 131072 + p];
        #pragma unroll
        for (int j = 0; j < 8; j++) s[j] += (float)e[j];
    }
    f32x4 r0, r1;
    #pragma unroll
    for (int j = 0; j < 4; j++) r0[j] = __builtin_amdgcn_rcpf(s[j]);
    #pragma unroll
    for (int j = 0; j < 4; j++) r1[j] = __builtin_amdgcn_rcpf(s[j + 4]);
    ((f32x4*)Srcp)[p * 2]     = r0;
    ((f32x4*)Srcp)[p * 2 + 1] = r1;
}

extern "C" void kernel_launch(void* const* d_in, const int* in_sizes, int n_in,
                              void* d_out, int out_size, void* d_ws, size_t ws_size,
                              hipStream_t stream)
{
    const float* x  = (const float*)d_in[0];
    const float* Wq = (const float*)d_in[1];
    const float* bq = (const float*)d_in[2];
    const float* Wk = (const float*)d_in[3];
    const float* bk = (const float*)d_in[4];
    const float* Wv = (const float*)d_in[5];
    const float* bv = (const float*)d_in[6];
    float* out = (float*)d_out;

    // Workspace layout (bytes):
    //   [0,4M)     Srcp fp32 (1024x1024)  -- overlaps xb region; xb is dead
    //   [0,16M)    xb   bf16 (32768x256)     before reduce_s writes Srcp
    //   [16M,32M)  qb \
    //   [32M,48M)  kb  } stride 16M (8388608 elem)
    //   [48M,64M)  vT (32,256,1024)
    //   [64M,128M) E  bf16 (32,1024,1024)
    //   [128M,+768K) Wqb/Wkb/Wvb bf16 contiguous
    //   [+768K,+771K) bpack fp32[768]
    char* ws = (char*)d_ws;
    float*  Srcp  = (float*) (ws);
    __bf16* xb    = (__bf16*)(ws);
    __bf16* qkv   = (__bf16*)(ws + (16u << 20));
    __bf16* E     = (__bf16*)(ws + (64u << 20));
    __bf16* Wqb   = (__bf16*)(ws + (128u << 20));
    float*  bpack = (float*) (ws + (128u << 20) + (3u << 18));

    // 1) converts + bias pack
    cvt_all<<<4194, 256, 0, stream>>>(x, Wq, Wk, Wv, bq, bk, bv, xb, Wqb, bpack);

    // 2) q/k/v projections, one launch (z picks W/bias/output path)
    gemm_nt<4, 0><<<dim3(256, 2, 3), 256, 0, stream>>>(xb, Wqb, qkv, bpack,
                                                       256, 256, 256, 256,
                                                       0, 131072, 8388608);

    // 3) E[b] = exp(q[b] @ k[b]^T), flat grid with z->XCD swizzle
    gemm_nt<2, 1><<<2048, 256, 0, stream>>>(qkv, qkv + 8388608, E, nullptr,
                                            256, 256, 1024, 256,
                                            262144, 262144, 1048576);

    // 4) Srcp = 1 / sum_b E  (xb dead by now; Srcp reuses its space)
    reduce_s<<<512, 256, 0, stream>>>(E, Srcp);

    // 5) out[b] = (E[b]*Srcp) @ vT[b]^T, normalization fused into A-staging
    gemm_pv<<<512, 256, 0, stream>>>(E, Srcp, qkv + 2 * 8388608, out);
}

// Round 5
// 192.278 us; speedup vs baseline: 1.2106x; 1.1102x over previous
//
#include <hip/hip_runtime.h>

typedef __bf16 bf16x8 __attribute__((ext_vector_type(8)));
typedef __bf16 bf16x4 __attribute__((ext_vector_type(4)));
typedef float  f32x4  __attribute__((ext_vector_type(4)));

#define BM 128
#define BN 128
#define BK 64

__device__ __forceinline__ void g2l16(const void* g, void* l) {
    __builtin_amdgcn_global_load_lds((const __attribute__((address_space(1))) void*)g,
                                     (__attribute__((address_space(3))) void*)l, 16, 0, 0);
}

// NT GEMM: C[i][j] = sum_k A[i*lda+k] * B[j*ldb+k]  (+ epilogue)
// 128x128 tile, BK=64, 4 waves 2x2, wave computes 64x64.
// LDS: unpadded [128][64] bf16, 16B-unit XOR swizzle (unit ^= row&7) applied
// at the global SOURCE column during global_load_lds staging and at fragment
// reads -> 0 bank conflicts (verified R2/R4).
// Epilogue: DIRECT global stores (R2-verified; R3's LDS roundtrip regressed).
// EPI: 2 = exp -> bf16 row-major store                      [logits -> E]
//      4 = +bias projection; z<2 bf16 row-major (q,k), z==2 transposed vT
// SWZ: 0 = plain 3D grid.
//      1 = XCD-sequential flat grid (logits): x=id%8 is the XCD slot; within
//          an XCD, 64 consecutive s-values form ONE batch (z = x + 8*(s>>6)),
//          so each XCD streams one batch at a time: q+k working set ~4MB = L2.
template<int EPI, int SWZ>
__global__ __launch_bounds__(256)
void gemm_nt(const __bf16* __restrict__ A, const __bf16* __restrict__ B,
             void* __restrict__ Cv, const float* __restrict__ bias,
             int lda, int ldb, int ldc, int K,
             long sA, long sB, long sC)
{
    __shared__ __align__(16) __bf16 As[BM * BK];
    __shared__ __align__(16) __bf16 Bs[BN * BK];

    const int tid  = threadIdx.x;
    const int w    = tid >> 6;
    const int lane = tid & 63;
    const int quad = lane >> 4;
    const int l16  = lane & 15;
    const int wm   = w & 1;
    const int wn   = w >> 1;

    int m0, n0, z;
    if constexpr (SWZ == 1) {
        const int id = blockIdx.x;
        const int x  = id & 7, s = id >> 3;
        z = x + ((s >> 6) << 3);
        const int t = s & 63;
        m0 = (t & 7) * BM;
        n0 = (t >> 3) * BN;
    } else {
        m0 = blockIdx.x * BM;
        n0 = blockIdx.y * BN;
        z  = blockIdx.z;
    }

    const __bf16* Ab = A + (size_t)z * sA;
    const __bf16* Bb = B + (size_t)z * sB;

    const int srow = (w << 3) + (lane >> 3);
    const int scol = ((lane & 7) ^ (lane >> 3)) << 3;
    char* ldsA = (char*)As + (size_t)w * 1024;
    char* ldsB = (char*)Bs + (size_t)w * 1024;

    const __bf16* Ag = Ab + (size_t)(m0 + srow) * lda + scol;
    const __bf16* Bg = Bb + (size_t)(n0 + srow) * ldb + scol;

    f32x4 acc[4][4] = {};

    for (int k0 = 0; k0 < K; k0 += BK) {
        __syncthreads();
        #pragma unroll
        for (int c = 0; c < 4; c++)
            g2l16(Ag + (size_t)(c * 32) * lda + k0, ldsA + c * 4096);
        #pragma unroll
        for (int c = 0; c < 4; c++)
            g2l16(Bg + (size_t)(c * 32) * ldb + k0, ldsB + c * 4096);
        __syncthreads();

        #pragma unroll
        for (int kk = 0; kk < BK; kk += 32) {
            const int ub = kk >> 3;
            bf16x8 a[4], b[4];
            #pragma unroll
            for (int mt = 0; mt < 4; mt++) {
                const int row = wm * 64 + mt * 16 + l16;
                const int cp  = ((quad + ub) ^ (row & 7)) << 3;
                a[mt] = *(const bf16x8*)&As[row * BK + cp];
            }
            #pragma unroll
            for (int nt = 0; nt < 4; nt++) {
                const int row = wn * 64 + nt * 16 + l16;
                const int cp  = ((quad + ub) ^ (row & 7)) << 3;
                b[nt] = *(const bf16x8*)&Bs[row * BK + cp];
            }
            #pragma unroll
            for (int mt = 0; mt < 4; mt++)
                #pragma unroll
                for (int nt = 0; nt < 4; nt++)
                    acc[mt][nt] = __builtin_amdgcn_mfma_f32_16x16x32_bf16(
                        a[mt], b[nt], acc[mt][nt], 0, 0, 0);
        }
    }

    // Epilogue. C/D layout (m89/m91): row = quad*4 + reg, col = l16.
    #pragma unroll
    for (int mt = 0; mt < 4; mt++) {
        const int mb = m0 + wm * 64 + mt * 16 + quad * 4;
        #pragma unroll
        for (int nt = 0; nt < 4; nt++) {
            const int n = n0 + wn * 64 + nt * 16 + l16;
            if constexpr (EPI == 2) {
                __bf16* C = (__bf16*)Cv + (size_t)z * sC;
                #pragma unroll
                for (int r = 0; r < 4; r++)
                    C[(size_t)(mb + r) * ldc + n] = (__bf16)__expf(acc[mt][nt][r]);
            } else {  // EPI == 4
                const float bn = bias[z * 256 + n];
                if (z < 2) {
                    __bf16* C = (__bf16*)Cv + (size_t)z * sC;
                    #pragma unroll
                    for (int r = 0; r < 4; r++)
                        C[(size_t)(mb + r) * ldc + n] = (__bf16)(acc[mt][nt][r] + bn);
                } else {
                    // vT[b][d=n][m]: batch stride 262144, d stride 1024
                    __bf16* C = (__bf16*)Cv + 2 * sC;
                    const int bidx = mb >> 10, mloc = mb & 1023;  // mb multiple of 4
                    bf16x4 pk;
                    #pragma unroll
                    for (int r = 0; r < 4; r++) pk[r] = (__bf16)(acc[mt][nt][r] + bn);
                    *(bf16x4*)(C + (size_t)bidx * 262144 + (size_t)n * 1024 + mloc) = pk;
                }
            }
        }
    }
}

// PV GEMM (plain NT, E already normalized): out[z][n,d] = attn[z] @ vT[z]^T.
// 128x64 tile -> grid 1024 = 4 blocks/CU (fixes R4's 2/CU latency bind).
// XCD-sequential swizzle: x=id%8, 32 consecutive s per batch.
__global__ __launch_bounds__(256)
void gemm_pv(const __bf16* __restrict__ E, const __bf16* __restrict__ vT,
             float* __restrict__ out)
{
    __shared__ __align__(16) __bf16 As[128 * 64];   // 16 KB
    __shared__ __align__(16) __bf16 Bs[64 * 64];    //  8 KB

    const int tid  = threadIdx.x;
    const int w    = tid >> 6;
    const int lane = tid & 63;
    const int quad = lane >> 4;
    const int l16  = lane & 15;
    const int wm   = w & 1;        // 64-row half
    const int wn   = w >> 1;       // 32-col half

    const int id = blockIdx.x;
    const int x  = id & 7, s = id >> 3;        // s: 0..127
    const int z  = x + ((s >> 5) << 3);        // 4 batches per XCD, sequential
    const int t  = s & 31;
    const int m0 = (t & 7) * 128;              // n-row tile
    const int n0 = (t >> 3) * 64;              // d-col tile

    const __bf16* Eb = E  + (size_t)z * 1048576;
    const __bf16* Vb = vT + (size_t)z * 262144;
    float*        Ob = out + (size_t)z * 262144;

    const int srow = (w << 3) + (lane >> 3);
    const int scol = ((lane & 7) ^ (lane >> 3)) << 3;
    char* ldsA = (char*)As + (size_t)w * 1024;
    char* ldsB = (char*)Bs + (size_t)w * 1024;

    const __bf16* Ag = Eb + (size_t)(m0 + srow) * 1024 + scol;
    const __bf16* Bg = Vb + (size_t)(n0 + srow) * 1024 + scol;

    f32x4 acc[4][2] = {};

    for (int k0 = 0; k0 < 1024; k0 += BK) {
        __syncthreads();
        #pragma unroll
        for (int c = 0; c < 4; c++)
            g2l16(Ag + (size_t)(c * 32) * 1024 + k0, ldsA + c * 4096);
        #pragma unroll
        for (int c = 0; c < 2; c++)
            g2l16(Bg + (size_t)(c * 32) * 1024 + k0, ldsB + c * 4096);
        __syncthreads();

        #pragma unroll
        for (int kk = 0; kk < BK; kk += 32) {
            const int ub = kk >> 3;
            bf16x8 a[4], b[2];
            #pragma unroll
            for (int mt = 0; mt < 4; mt++) {
                const int row = wm * 64 + mt * 16 + l16;
                const int cp  = ((quad + ub) ^ (row & 7)) << 3;
                a[mt] = *(const bf16x8*)&As[row * BK + cp];
            }
            #pragma unroll
            for (int nt = 0; nt < 2; nt++) {
                const int row = wn * 32 + nt * 16 + l16;
                const int cp  = ((quad + ub) ^ (row & 7)) << 3;
                b[nt] = *(const bf16x8*)&Bs[row * BK + cp];
            }
            #pragma unroll
            for (int mt = 0; mt < 4; mt++)
                #pragma unroll
                for (int nt = 0; nt < 2; nt++)
                    acc[mt][nt] = __builtin_amdgcn_mfma_f32_16x16x32_bf16(
                        a[mt], b[nt], acc[mt][nt], 0, 0, 0);
        }
    }

    #pragma unroll
    for (int mt = 0; mt < 4; mt++) {
        const int mb = m0 + wm * 64 + mt * 16 + quad * 4;
        #pragma unroll
        for (int nt = 0; nt < 2; nt++) {
            const int n = n0 + wn * 32 + nt * 16 + l16;
            #pragma unroll
            for (int r = 0; r < 4; r++)
                Ob[(size_t)(mb + r) * 256 + n] = acc[mt][nt][r];
        }
    }
}

// One launch: x -> bf16, Wq/Wk/Wv -> bf16, pack 3 fp32 biases.
__global__ __launch_bounds__(256)
void cvt_all(const float* __restrict__ x,
             const float* __restrict__ Wq, const float* __restrict__ Wk,
             const float* __restrict__ Wv,
             const float* __restrict__ bq, const float* __restrict__ bk,
             const float* __restrict__ bv,
             __bf16* __restrict__ xb, __bf16* __restrict__ Wqb,
             float* __restrict__ bpack)
{
    const int i = blockIdx.x * 256 + threadIdx.x;
    if (i < 1073152) {
        const float* s; __bf16* d; int off;
        if (i < 1048576)      { s = x;  d = xb;            off = i; }
        else if (i < 1056768) { s = Wq; d = Wqb;           off = i - 1048576; }
        else if (i < 1064960) { s = Wk; d = Wqb + 131072;  off = i - 1056768; }
        else                  { s = Wv; d = Wqb + 262144;  off = i - 1064960; }
        const float4* s4 = (const float4*)s;
        const float4 f0 = s4[off * 2], f1 = s4[off * 2 + 1];
        bf16x8 o;
        o[0] = (__bf16)f0.x; o[1] = (__bf16)f0.y; o[2] = (__bf16)f0.z; o[3] = (__bf16)f0.w;
        o[4] = (__bf16)f1.x; o[5] = (__bf16)f1.y; o[6] = (__bf16)f1.z; o[7] = (__bf16)f1.w;
        ((bf16x8*)d)[off] = o;
    } else if (i < 1073344) {
        const int j = i - 1073152;
        const int sel = j >> 6, jj = j & 63;
        const float* s = sel == 0 ? bq : (sel == 1 ? bk : bv);
        ((float4*)bpack)[j] = ((const float4*)s)[jj];
    }
}

// Batch-axis softmax: S[n,m] = sum_b E[b,n,m]; E <- E/S. Single pass:
// all 32 batch slices cached in registers (32 x bf16x8 = 128 VGPR).
__global__ __launch_bounds__(256)
void softmax_norm(__bf16* __restrict__ E)
{
    const size_t p = (size_t)blockIdx.x * 256 + threadIdx.x;
    bf16x8* E8 = (bf16x8*)E;
    bf16x8 e[32];
    #pragma unroll
    for (int b = 0; b < 32; b++) e[b] = E8[(size_t)b * 131072 + p];
    float s[8] = {0.f, 0.f, 0.f, 0.f, 0.f, 0.f, 0.f, 0.f};
    #pragma unroll
    for (int b = 0; b < 32; b++)
        #pragma unroll
        for (int j = 0; j < 8; j++) s[j] += (float)e[b][j];
    float rs[8];
    #pragma unroll
    for (int j = 0; j < 8; j++) rs[j] = __builtin_amdgcn_rcpf(s[j]);
    #pragma unroll
    for (int b = 0; b < 32; b++) {
        bf16x8 o = e[b];
        #pragma unroll
        for (int j = 0; j < 8; j++) o[j] = (__bf16)((float)o[j] * rs[j]);
        E8[(size_t)b * 131072 + p] = o;
    }
}

extern "C" void kernel_launch(void* const* d_in, const int* in_sizes, int n_in,
                              void* d_out, int out_size, void* d_ws, size_t ws_size,
                              hipStream_t stream)
{
    const float* x  = (const float*)d_in[0];
    const float* Wq = (const float*)d_in[1];
    const float* bq = (const float*)d_in[2];
    const float* Wk = (const float*)d_in[3];
    const float* bk = (const float*)d_in[4];
    const float* Wv = (const float*)d_in[5];
    const float* bv = (const float*)d_in[6];
    float* out = (float*)d_out;

    // Workspace layout (bytes):
    //   [0,16M)    xb   bf16 (32768x256)
    //   [16M,32M)  qb \
    //   [32M,48M)  kb  } stride 16M (8388608 elem)
    //   [48M,64M)  vT (32,256,1024)
    //   [64M,128M) E  bf16 (32,1024,1024)
    //   [128M,+768K) Wqb/Wkb/Wvb bf16 contiguous
    //   [+768K,+771K) bpack fp32[768]
    char* ws = (char*)d_ws;
    __bf16* xb    = (__bf16*)(ws);
    __bf16* qkv   = (__bf16*)(ws + (16u << 20));
    __bf16* E     = (__bf16*)(ws + (64u << 20));
    __bf16* Wqb   = (__bf16*)(ws + (128u << 20));
    float*  bpack = (float*) (ws + (128u << 20) + (3u << 18));

    // 1) converts + bias pack
    cvt_all<<<4194, 256, 0, stream>>>(x, Wq, Wk, Wv, bq, bk, bv, xb, Wqb, bpack);

    // 2) q/k/v projections, one launch (z picks W/bias/output path)
    gemm_nt<4, 0><<<dim3(256, 2, 3), 256, 0, stream>>>(xb, Wqb, qkv, bpack,
                                                       256, 256, 256, 256,
                                                       0, 131072, 8388608);

    // 3) E[b] = exp(q[b] @ k[b]^T), XCD-sequential flat grid
    gemm_nt<2, 1><<<2048, 256, 0, stream>>>(qkv, qkv + 8388608, E, nullptr,
                                            256, 256, 1024, 256,
                                            262144, 262144, 1048576);

    // 4) batch-axis softmax normalize in place (single 128MB streaming pass)
    softmax_norm<<<512, 256, 0, stream>>>(E);

    // 5) out[b] = attn[b] @ vT[b]^T, plain GEMM, 128x64 tiles, grid 1024
    gemm_pv<<<1024, 256, 0, stream>>>(E, qkv + 2 * 8388608, out);
}